// Round 2
// baseline (630.550 us; speedup 1.0000x reference)
//
#include <hip/hip_runtime.h>

typedef __attribute__((ext_vector_type(8))) short  s8v;   // 8 x bf16 bits
typedef __attribute__((ext_vector_type(4))) float  f4v;
typedef __attribute__((ext_vector_type(4))) unsigned short u4v;

#define XH 256
#define XW 256
#define XC 64
#define PLANE 65536
#define PCW 66          // padded tile width (64 + 2 halo)

__device__ __forceinline__ unsigned short f2bf(float f){
  unsigned int u = __builtin_bit_cast(unsigned int, f);
  return (unsigned short)((u + 0x7FFFu + ((u >> 16) & 1u)) >> 16);  // RNE
}
__device__ __forceinline__ float bf2f(unsigned short h){
  unsigned int u = ((unsigned int)h) << 16;
  return __builtin_bit_cast(float, u);
}

// ---------------- K1: per-(b,c) plane mean ----------------
__global__ __launch_bounds__(256) void pool_k(const float* __restrict__ x,
                                              float* __restrict__ pooled){
  int plane = blockIdx.x, t = threadIdx.x;
  const f4v* p = (const f4v*)(x + (size_t)plane * PLANE);
  float s = 0.f;
  #pragma unroll 8
  for(int it = 0; it < 64; ++it){
    f4v v = p[t + (it << 8)];
    s += v[0] + v[1] + v[2] + v[3];
  }
  #pragma unroll
  for(int m = 32; m >= 1; m >>= 1) s += __shfl_xor(s, m);
  __shared__ float ps[4];
  if((t & 63) == 0) ps[t >> 6] = s;
  __syncthreads();
  if(t == 0) pooled[plane] = (ps[0] + ps[1] + ps[2] + ps[3]) * (1.f / 65536.f);
}

// ---------------- K2: direction MLP + BN-folded weight pack ----------------
// PK layout (bf16): byte = s*4096 + n*64 + g*16 + j*2   (s=K32-step 0..17, n=oc,
// g=lane>>4, j=0..7).  k within step = 8g + j ; global k = 32 s + 8 g + j =
// tap*64 + c with tap = s>>1, c = 32*(s&1) + 8 g + j.
__global__ __launch_bounds__(256) void prep_k(const float* __restrict__ convw,
    const float* __restrict__ convb, const float* __restrict__ gamma,
    const float* __restrict__ beta,  const float* __restrict__ mean,
    const float* __restrict__ var,   const float* __restrict__ d1w,
    const float* __restrict__ d1b,   const float* __restrict__ d2w,
    const float* __restrict__ d2b,   const float* __restrict__ pooled,
    float* __restrict__ dirv, float* __restrict__ bias2,
    unsigned short* __restrict__ pk, float* __restrict__ outdir){
  int blk = blockIdx.x, t = threadIdx.x;
  if(blk == 0){
    if(t < 16){
      float logit = d2b[0];
      for(int o = 0; o < 8; ++o){
        float a = d1b[o];
        for(int c = 0; c < 64; ++c) a = fmaf(pooled[t * 64 + c], d1w[o * 64 + c], a);
        logit = fmaf(fmaxf(a, 0.f), d2w[o], logit);
      }
      float dv = 1.f / (1.f + __expf(-logit));
      dirv[t] = dv;
      outdir[t] = dv;          // direction output (tuple tail)
    } else if(t >= 64 && t < 128){
      int oc = t - 64;
      float sc = gamma[oc] * rsqrtf(var[oc] + 1e-5f);
      bias2[oc] = (convb[oc] - mean[oc]) * sc + beta[oc];
    }
  } else {
    int idx = ((blk - 1) << 8) + t;              // < 36864
    int j = idx & 7, g = (idx >> 3) & 3, n = (idx >> 5) & 63, s = idx >> 11;
    int c = ((s & 1) << 5) + (g << 3) + j, tap = s >> 1;
    float sc = gamma[n] * rsqrtf(var[n] + 1e-5f);
    pk[idx] = f2bf(convw[(n * 64 + c) * 9 + tap] * sc);
  }
}

// ---------------- K3: fused conv+BN+relu+attn+sigmoid+mul ----------------
// Block = 256 thr (4 waves). Tile = 4 rows x 64 cols of one image. Wave wv
// owns tile row wv.  LDS xs: [pix = hh*66+pc][64 ch] bf16, swizzled
// byte ^= (pix&7)<<4 within each pixel's 128B row.
__global__ __launch_bounds__(256, 3) void main_k(const float* __restrict__ x,
    const float* __restrict__ attnw, const float* __restrict__ attnb,
    const float* __restrict__ dirv,  const float* __restrict__ bias2,
    const unsigned short* __restrict__ pk, float* __restrict__ out){
  __shared__ __align__(16) char lds[6 * PCW * 128 + 4 * 64 * 4];
  float* att_s = (float*)(lds + 6 * PCW * 128);

  const int bid = blockIdx.x;
  const int bs  = ((bid & 7) << 9) | (bid >> 3);     // XCD swizzle (4096 % 8 == 0)
  const int wblk = bs & 3, hblk = (bs >> 2) & 63, b = bs >> 8;
  const int w0 = wblk << 6, h0 = hblk << 2;
  const int t = threadIdx.x, lane = t & 63, wv = t >> 6;
  const int lm = lane & 15, lg = lane >> 4;
  const size_t bbase = (size_t)b * XC * PLANE;

  // ---- stage x halo (6 rows x 66 cols x 64 ch) as bf16, transposed to [pix][c]
  #pragma unroll 1
  for(int it = 0; it < 7; ++it){
    int task = t + (it << 8);
    if(task < 1728){                       // 16 cgrp * 6 hh * 18 chunks
      unsigned ut = (unsigned)task;
      int chunk = ut % 18u; unsigned rem = ut / 18u;
      int hh = rem % 6u;    int cgrp = rem / 6u;
      int hhg = h0 - 1 + hh;
      int wcg = w0 - 4 + (chunk << 2);     // 16B-aligned float4 start
      f4v v0 = {0,0,0,0}, v1 = {0,0,0,0}, v2 = {0,0,0,0}, v3 = {0,0,0,0};
      if(hhg >= 0 && hhg < XH && wcg >= 0 && wcg + 3 < XW){
        const float* bp = x + bbase + (size_t)(cgrp << 2) * PLANE + (size_t)hhg * XW + wcg;
        v0 = *(const f4v*)bp;
        v1 = *(const f4v*)(bp + PLANE);
        v2 = *(const f4v*)(bp + 2 * PLANE);
        v3 = *(const f4v*)(bp + 3 * PLANE);
      }
      #pragma unroll
      for(int e = 0; e < 4; ++e){
        int pc = (chunk << 2) - 3 + e;
        if(pc >= 0 && pc < PCW){
          int pix = hh * PCW + pc;
          int bo = pix * 128 + ((cgrp << 3) ^ ((pix & 7) << 4));
          u4v pv; pv[0] = f2bf(v0[e]); pv[1] = f2bf(v1[e]);
                  pv[2] = f2bf(v2[e]); pv[3] = f2bf(v3[e]);
          *(u4v*)(lds + bo) = pv;
        }
      }
    }
  }
  __syncthreads();

  // ---- implicit-GEMM K loop: 18 steps of K=32 (2 per tap), no barriers
  f4v acc[4][4];
  #pragma unroll
  for(int i = 0; i < 4; ++i)
    #pragma unroll
    for(int j = 0; j < 4; ++j) acc[i][j] = (f4v){0.f, 0.f, 0.f, 0.f};

  const char* pkl = (const char*)pk + lm * 64 + (lg << 4);
  const int pixb = (wv + 1) * PCW + lm + 1;
  const int cbg  = lg << 4;

  s8v bA[4], bB[4];
  #pragma unroll
  for(int jn = 0; jn < 4; ++jn) bA[jn] = *(const s8v*)(pkl + (jn << 10));

#define ALOAD(AFR, D, CB) { \
    _Pragma("unroll") \
    for(int i = 0; i < 4; ++i){ int pix = pixb + (i << 4) + (D); \
      AFR[i] = *(const s8v*)(lds + pix * 128 + ((CB) ^ ((pix & 7) << 4))); } }
#define BLOAD(BUF, S) { \
    _Pragma("unroll") \
    for(int jn = 0; jn < 4; ++jn) BUF[jn] = *(const s8v*)(pkl + ((S) << 12) + (jn << 10)); }
#define MF(AFR, BUF) { \
    _Pragma("unroll") \
    for(int i = 0; i < 4; ++i){ _Pragma("unroll") for(int j = 0; j < 4; ++j) \
      acc[i][j] = __builtin_amdgcn_mfma_f32_16x16x32_bf16(AFR[i], BUF[j], acc[i][j], 0, 0, 0); } }

  #pragma unroll 1
  for(int p = 0; p < 9; ++p){              // p = tap; steps s = 2p, 2p+1
    const int dh = p / 3 - 1, dw = p % 3 - 1;
    const int d = dh * PCW + dw;
    s8v afr[4];
    ALOAD(afr, d, cbg);                    // even step: channels 0..31
    BLOAD(bB, 2 * p + 1);                  // prefetch odd-step weights
    MF(afr, bA);
    ALOAD(afr, d, cbg + 64);               // odd step: channels 32..63
    if(p < 8) BLOAD(bA, 2 * p + 2);        // prefetch next tap's even step
    MF(afr, bB);
  }

  // ---- epilogue: att = sum_oc attn_w[oc] * relu(z + bias2[oc])
  float aw[4], bz[4];
  #pragma unroll
  for(int j = 0; j < 4; ++j){ aw[j] = attnw[(j << 4) + lm]; bz[j] = bias2[(j << 4) + lm]; }
  #pragma unroll
  for(int i = 0; i < 4; ++i){
    #pragma unroll
    for(int r = 0; r < 4; ++r){
      float lsum = 0.f;
      #pragma unroll
      for(int j = 0; j < 4; ++j)
        lsum = fmaf(aw[j], fmaxf(acc[i][j][r] + bz[j], 0.f), lsum);
      lsum += __shfl_xor(lsum, 8);
      lsum += __shfl_xor(lsum, 4);
      lsum += __shfl_xor(lsum, 2);
      lsum += __shfl_xor(lsum, 1);
      // pixel col = 16 i + 4 lg + r ; one lane per (i,r) writes
      if(lm == (i << 2) + r) att_s[(wv << 6) + (i << 4) + (lg << 2) + r] = lsum;
    }
  }
  __syncthreads();

  // ---- output: out = x * sigmoid((att + attn_b) * mask)
  const int col = lane, row = wv;
  const float dir = dirv[b];
  const int h = h0 + row;
  const float jf = (float)h * (1.f / 256.f);
  const float maskv = (dir > 0.5f) ? (0.5f + 0.5f * jf) : (1.f - 0.5f * jf);
  const float att = att_s[(row << 6) + col] + attnb[0];
  const float sg = 1.f / (1.f + __expf(-att * maskv));
  const int pix = (row + 1) * PCW + (col + 1);
  const char* xr = lds + pix * 128;
  const int swz = (pix & 7) << 4;
  float* op = out + bbase + (size_t)h * XW + w0 + col;
  #pragma unroll
  for(int k = 0; k < 8; ++k){
    s8v v = *(const s8v*)(xr + ((k << 4) ^ swz));
    #pragma unroll
    for(int e = 0; e < 8; ++e){
      op[(size_t)((k << 3) + e) * PLANE] = bf2f((unsigned short)v[e]) * sg;
    }
  }
#undef ALOAD
#undef BLOAD
#undef MF
}

extern "C" void kernel_launch(void* const* d_in, const int* in_sizes, int n_in,
                              void* d_out, int out_size, void* d_ws, size_t ws_size,
                              hipStream_t stream){
  const float* x     = (const float*)d_in[0];
  const float* convw = (const float*)d_in[1];
  const float* convb = (const float*)d_in[2];
  const float* gamma = (const float*)d_in[3];
  const float* beta  = (const float*)d_in[4];
  const float* mean  = (const float*)d_in[5];
  const float* var   = (const float*)d_in[6];
  const float* attnw = (const float*)d_in[7];
  const float* attnb = (const float*)d_in[8];
  const float* d1w   = (const float*)d_in[9];
  const float* d1b   = (const float*)d_in[10];
  const float* d2w   = (const float*)d_in[11];
  const float* d2b   = (const float*)d_in[12];
  float* out = (float*)d_out;
  char*  ws  = (char*)d_ws;
  float* pooled = (float*)ws;                       // 1024 f32
  float* dirv   = (float*)(ws + 4096);              // 16 f32
  float* bias2  = (float*)(ws + 4160);              // 64 f32
  unsigned short* pk = (unsigned short*)(ws + 4416);// 36864 bf16 = 73728 B
  float* outdir = out + (size_t)16 * 64 * 256 * 256;

  pool_k<<<1024, 256, 0, stream>>>(x, pooled);
  prep_k<<<145, 256, 0, stream>>>(convw, convb, gamma, beta, mean, var,
                                  d1w, d1b, d2w, d2b, pooled, dirv, bias2, pk, outdir);
  main_k<<<4096, 256, 0, stream>>>(x, attnw, attnb, dirv, bias2, pk, out);
}